// Round 14
// baseline (108.326 us; speedup 1.0000x reference)
//
#include <hip/hip_runtime.h>
#include <hip/hip_bf16.h>
#include <hip/hip_fp16.h>

// KAN harmonic-basis GEMM, v17: v16 + TALL WAVES (64 rows x 32 cols) to halve
// the LDS-read term (now the largest ledger entry).
// out[b,h] = sum_{d,f} basis(x[b,d])[f] * W[d,f,h] + sum_d b[d,h]
//
// f=0 + bias -> fp32 partials c_part[8][256], summed in GEMM epilogue.
// f=1..10    -> f16 MFMA GEMM, M=16384, N=256, K=2560.
//
// v17 (v16 ledger @35us: LDS-read 12.8 (largest), DMA 9, VALU 4, MFMA 2.6.
// Per-CU LDS-read = K*2B*BN*(BM/rows_per_wave) -> taller waves read less):
//   - 8 waves = rg(2 row-groups of 64) x cg(4 col-groups of 32). Per wave:
//     4 i-frags x 2 j-frags. LDS reads/CU 2.62 -> 1.31 MB (-6.4us).
//     Trig dup 2x -> 4x (+~3us on a now-small VALU term). MFMA/DMA/staging
//     layout unchanged.
//   - v16's verified pieces kept: hw v_sin/v_cos (|x|/2pi < 1 rev),
//     f16-resident state feeding mfma_f32_16x16x32_f16 directly, f16 B,
//     BM=128 x BN=128, 1 block/CU (96KB pad), 5-slot ring, stage-ahead-3,
//     one s_barrier per phase.
//   - vmcnt audit (stage = 2 loads/wave/phase; x = 8 loads at q==2):
//     steady: q0 enter {S(p),S(p+1),S(p+2)}=6 (+x8 if post-q2 -> retired at
//     q4), +S(p+3)=8, vmcnt(6) retires S(p). q2: enter 6, +x8+S=16,
//     vmcnt(14) retires S(p). q3: enter 14, +2=16, vmcnt(14) retires S(p+1).
//     q4: enter 14, +2=16, vmcnt(6) retires S(p+2)+x8 (x done before next
//     q0's sincos). dt=0: prologue x8+S0..2=14; q0 issues S3->16, vmcnt(6)
//     retires x8+S0. Waits: 6,6,14,14,6.

#define BDIM 16384
#define DDIM 256
#define HOUT 256
#define NKT  80
#define BM 128
#define BN 128

typedef _Float16 halfx8 __attribute__((ext_vector_type(8)));
typedef float floatx4 __attribute__((ext_vector_type(4)));

__device__ __forceinline__ unsigned short f2h(float f) {
    union { _Float16 h; unsigned short u; } v;
    v.h = (_Float16)f;
    return v.u;
}

#define INV2PI 0.15915494309189535f

__device__ __forceinline__ void hwsincos(float x, float* s, float* c) {
    const float r = x * INV2PI;      // revolutions; |r| < 1 for N(0,1) inputs
    float sv, cv;
    asm("v_sin_f32 %0, %1" : "=v"(sv) : "v"(r));
    asm("v_cos_f32 %0, %1" : "=v"(cv) : "v"(r));
    *s = sv; *c = cv;
}

// grid 328 x 256 threads.
// blocks [0,320): kt = bid>>2, sub = bid&3:
//   Wfrag[kt][n=t][dd = sub*8 .. +8] = f16(W[dtile*32+dd][kt%10+1][n])
// blocks [320,328): p = bid-320; c_part[p][h] = sum_{d in p*32..+32} W[d][0][h]+b[d][h]
__global__ void prep_kernel(const float* __restrict__ W, const float* __restrict__ bias,
                            unsigned short* __restrict__ Wfrag, float* __restrict__ c_part) {
    const int bid = blockIdx.x;
    const int t = threadIdx.x;
    if (bid < 4 * NKT) {
        const int kt = bid >> 2;
        const int sub = bid & 3;
        const int dtile = kt / 10;
        const int f = kt - dtile * 10 + 1;
        const int d0 = dtile * 32 + sub * 8;
        const float* wsrc = W + ((size_t)d0 * 11 + f) * 256 + t;
        union { unsigned short s[8]; int4 v; } buf;
#pragma unroll
        for (int dd = 0; dd < 8; ++dd)
            buf.s[dd] = f2h(wsrc[(size_t)dd * 11 * 256]);
        *(int4*)(Wfrag + ((size_t)kt * 256 + t) * 32 + sub * 8) = buf.v;
    } else {
        const int p = bid - 4 * NKT;
        float acc = 0.f;
#pragma unroll
        for (int dd = 0; dd < 32; ++dd) {
            const int d = p * 32 + dd;
            acc += W[(size_t)(d * 11) * 256 + t] + bias[(size_t)d * 256 + t];
        }
        c_part[p * 256 + t] = acc;
    }
}

__global__ __launch_bounds__(512, 2)
void kan_gemm(const float* __restrict__ x, const unsigned short* __restrict__ Wfrag,
              const float* __restrict__ c_part, float* __restrict__ out) {
    // 5-slot ring of 16KB phases; 6th slot = pad to 96KB -> 1 block/CU forced.
    __shared__ unsigned short Bs[6][2 * 8 * 512];

    const int t = threadIdx.x;
    const int m0 = blockIdx.x * BM;
    const int h0 = blockIdx.y * BN;

    const int lane = t & 63;
    const int wave = t >> 6;         // 0..7
    const int rg = wave >> 2;        // row group: rows m0 + rg*64 .. +64
    const int cg = wave & 3;         // col group: cols h0 + cg*32 .. +32
    const int l15 = lane & 15;
    const int koff = lane >> 4;

    floatx4 acc[4][2];
#pragma unroll
    for (int i = 0; i < 4; ++i)
#pragma unroll
        for (int j = 0; j < 2; ++j)
            acc[i][j] = (floatx4){0.f, 0.f, 0.f, 0.f};

    // lane's x rows: i -> m0 + rg*64 + i*16 + l15; d-slots koff*8..+8
    const float* xr0 = x + (size_t)(m0 + rg * 64 + l15) * DDIM + koff * 8;

    // ---- prologue: x (8 loads) FIRST, then stages S0,S1,S2 (6 loads) ----
    float4 xn[8];
#pragma unroll
    for (int i = 0; i < 4; ++i) {
        xn[2 * i]     = *(const float4*)(xr0 + (size_t)i * 16 * DDIM + 0);
        xn[2 * i + 1] = *(const float4*)(xr0 + (size_t)i * 16 * DDIM + 4);
    }

#pragma unroll
    for (int p = 0; p < 3; ++p) {
#pragma unroll
        for (int s = 0; s < 2; ++s) {
            const int c = wave * 2 + s;
            const int ktl = c >> 3;
            const int f = c & 7;
            const unsigned short* g = Wfrag + (size_t)(p * 2 + ktl) * 8192
                                    + (h0 + f * 16 + l15) * 32 + koff * 8;
            __builtin_amdgcn_global_load_lds((const void*)g,
                (void*)(&Bs[p][0] + c * 512), 16, 0, 0);
        }
    }

    // f16-resident harmonic state: pair p in [0,16): i-frag = p>>2, holds
    // elems {2*(p&3), 2*(p&3)+1} of that row's 8 d-slots.
    __half2 s1h[16], c1h[16], skh[16], ckh[16];

#pragma unroll 1
    for (int dt = 0; dt < 8; ++dt) {
#pragma unroll
        for (int q = 0; q < 5; ++q) {
            // phase p = dt*5 + q; compute slot = q; write slot = (q+3)%5.

            // x prefetch for next dtile at q==2 (before stage issue).
            if (q == 2) {
                const int dn = (dt < 7) ? dt + 1 : 7;
#pragma unroll
                for (int i = 0; i < 4; ++i) {
                    xn[2 * i]     = *(const float4*)(xr0 + (size_t)i * 16 * DDIM + dn * 32 + 0);
                    xn[2 * i + 1] = *(const float4*)(xr0 + (size_t)i * 16 * DDIM + dn * 32 + 4);
                }
            }

            // ---- issue stage(p+3) into slot (q+3)%5 (clamped tail) ----
            {
                int pt = dt * 5 + q + 3;
                if (pt > 39) pt = 39;
#pragma unroll
                for (int s = 0; s < 2; ++s) {
                    const int c = wave * 2 + s;
                    const int ktl = c >> 3;
                    const int f = c & 7;
                    const unsigned short* g = Wfrag + (size_t)(pt * 2 + ktl) * 8192
                                            + (h0 + f * 16 + l15) * 32 + koff * 8;
                    __builtin_amdgcn_global_load_lds((const void*)g,
                        (void*)(&Bs[(q + 3) % 5][0] + c * 512), 16, 0, 0);
                }
            }

            // ---- counted wait (audited: 6,6,14,14,6) + publish barrier ----
            __builtin_amdgcn_sched_barrier(0);
            if (q == 2 || q == 3) {
                asm volatile("s_waitcnt vmcnt(14)" ::: "memory");
            } else {
                asm volatile("s_waitcnt vmcnt(6)" ::: "memory");
            }
            __builtin_amdgcn_s_barrier();
            __builtin_amdgcn_sched_barrier(0);

            if (q == 0) {
                // ---- dtile start: hw sincos of 32 elems -> f16 state ----
#pragma unroll
                for (int i = 0; i < 4; ++i) {
                    const float xv[8] = {xn[2 * i].x, xn[2 * i].y, xn[2 * i].z, xn[2 * i].w,
                                         xn[2 * i + 1].x, xn[2 * i + 1].y, xn[2 * i + 1].z, xn[2 * i + 1].w};
#pragma unroll
                    for (int pp = 0; pp < 4; ++pp) {
                        float s0, c0, s1, c1;
                        hwsincos(xv[2 * pp], &s0, &c0);
                        hwsincos(xv[2 * pp + 1], &s1, &c1);
                        const __half2 sh = __floats2half2_rn(s0, s1);
                        const __half2 ch = __floats2half2_rn(c0, c1);
                        s1h[i * 4 + pp] = sh; c1h[i * 4 + pp] = ch;
                        skh[i * 4 + pp] = sh; ckh[i * 4 + pp] = ch;
                    }
                }
            }

            // ---- compute 2 kt (harmonic q+1: sin then cos); A = state direct ----
#pragma unroll
            for (int s = 0; s < 2; ++s) {
                union { __half2 h2[4]; halfx8 v; } a[4];
                if (s == 0) {
#pragma unroll
                    for (int i = 0; i < 4; ++i)
#pragma unroll
                        for (int pp = 0; pp < 4; ++pp) a[i].h2[pp] = skh[i * 4 + pp];
                } else {
#pragma unroll
                    for (int i = 0; i < 4; ++i)
#pragma unroll
                        for (int pp = 0; pp < 4; ++pp) a[i].h2[pp] = ckh[i * 4 + pp];
                }

                // this cg's 2 col-chunks (f = cg*2, cg*2+1)
                const unsigned short* fb = &Bs[q][(s * 8 + cg * 2) * 512 + lane * 8];
                const halfx8 b0 = *(const halfx8*)(fb);
                const halfx8 b1 = *(const halfx8*)(fb + 512);

#pragma unroll
                for (int i = 0; i < 4; ++i) {
                    acc[i][0] = __builtin_amdgcn_mfma_f32_16x16x32_f16(a[i].v, b0, acc[i][0], 0, 0, 0);
                    acc[i][1] = __builtin_amdgcn_mfma_f32_16x16x32_f16(a[i].v, b1, acc[i][1], 0, 0, 0);
                }

                // advance harmonic k -> k+1 after the cos emit (except k=5):
                // ns = sk*c1 + ck*s1 ; nc = ck*c1 - sk*s1 (packed fp16)
                if (s == 1 && q < 4) {
#pragma unroll
                    for (int p = 0; p < 16; ++p) {
                        const __half2 t0 = __hmul2(ckh[p], s1h[p]);
                        const __half2 t1 = __hmul2(skh[p], s1h[p]);
                        const __half2 ns = __hfma2(skh[p], c1h[p], t0);
                        const __half2 nc = __hfma2(ckh[p], c1h[p], __hneg2(t1));
                        skh[p] = ns;
                        ckh[p] = nc;
                    }
                }
            }
        }
    }

    // drain redundant tail DMAs
    asm volatile("s_waitcnt vmcnt(0)" ::: "memory");

    // ---- epilogue: C/D layout col=lane&15, row=(lane>>4)*4+reg ----
    float cj[2];
#pragma unroll
    for (int j = 0; j < 2; ++j) {
        const int col = h0 + cg * 32 + j * 16 + l15;
        float s = 0.f;
#pragma unroll
        for (int q = 0; q < 8; ++q) s += c_part[q * 256 + col];
        cj[j] = s;
    }
#pragma unroll
    for (int i = 0; i < 4; ++i) {
        const int row0 = m0 + rg * 64 + i * 16 + koff * 4;
#pragma unroll
        for (int j = 0; j < 2; ++j) {
            const int col = h0 + cg * 32 + j * 16 + l15;
#pragma unroll
            for (int r = 0; r < 4; ++r)
                out[(size_t)(row0 + r) * HOUT + col] = acc[i][j][r] + cj[j];
        }
    }
}

extern "C" void kernel_launch(void* const* d_in, const int* in_sizes, int n_in,
                              void* d_out, int out_size, void* d_ws, size_t ws_size,
                              hipStream_t stream) {
    const float* x = (const float*)d_in[0];
    const float* W = (const float*)d_in[1];
    const float* b = (const float*)d_in[2];
    float* out = (float*)d_out;

    unsigned short* Wfrag = (unsigned short*)d_ws;                      // 1,310,720 B
    float* c_part = (float*)((char*)d_ws + (size_t)NKT * 256 * 32 * 2); // 8 KB

    prep_kernel<<<4 * NKT + 8, 256, 0, stream>>>(W, b, Wfrag, c_part);
    kan_gemm<<<dim3(BDIM / BM, HOUT / BN), 512, 0, stream>>>(x, Wfrag, c_part, out);
}

// Round 15
// 100.911 us; speedup vs baseline: 1.0735x; 1.0735x over previous
//
#include <hip/hip_runtime.h>
#include <hip/hip_bf16.h>
#include <hip/hip_fp16.h>

// KAN harmonic-basis GEMM, v18: v16 compute (verified optimum wave shape
// 32r x 64c, hw trig, f16-direct A) + coarser 5-kt phases: 16 barriers
// instead of 40, 3-slot x 40KB rotating LDS ring.
// out[b,h] = sum_{d,f} basis(x[b,d])[f] * W[d,f,h] + sum_d b[d,h]
//
// f=0 + bias -> fp32 partials c_part[8][256], summed in GEMM epilogue.
// f=1..10    -> f16 MFMA GEMM, M=16384, N=256, K=2560.
//
// v18 (v17 post-mortem: tall waves sold the cheap LDS term to double the
// expensive VALU term -> revert to v16 shape. v16's residual overhead:
// 40 phase-boundaries (wait+barrier+schedule restart) for 80 kt):
//   - Phase = 5 kt (half a dtile) = 40KB staged. 16 phases. Ring = 3 slots
//     x 40KB = 122,880 B (1 block/CU). Slots rotate via explicit pointer
//     swap (cur/nxt/thr) -- no runtime-indexed arrays.
//   - Order per phase (proven v12 discipline): issue S(p+1) -> counted wait
//     -> s_barrier -> compute. WAR: S(p+1) writes slot last read at
//     compute(p-2), sealed by barrier(p-1). RAW: own loads by vmcnt, other
//     waves' by their vmcnt + the barrier.
//   - x prefetch (4 loads) on ODD phases (consumed by next even phase's
//     sincos; never overwrites registers a pending sincos still reads).
//   - vmcnt audit: prologue x0(4)+S0(5)=9. Even p: enter {x?,S(p),S(p+1)}
//     issue-> wait vmcnt(5) retires S(p)+x (sincos safe). Odd p: enter
//     {S(p)}, issue S(p+1)+x -> 14, wait vmcnt(9) retires S(p).
//   - Stage: 40 chunks (1KB: 16 cols x 32 K) per phase; wave stages 5
//     (c = wave*5+s, ktl = c>>3, f = c&7), reads 20 (its wc's 4 per kt).

#define BDIM 16384
#define DDIM 256
#define HOUT 256
#define NKT  80
#define BM 128
#define BN 128

typedef _Float16 halfx8 __attribute__((ext_vector_type(8)));
typedef float floatx4 __attribute__((ext_vector_type(4)));

__device__ __forceinline__ unsigned short f2h(float f) {
    union { _Float16 h; unsigned short u; } v;
    v.h = (_Float16)f;
    return v.u;
}

#define INV2PI 0.15915494309189535f

__device__ __forceinline__ void hwsincos(float x, float* s, float* c) {
    const float r = x * INV2PI;      // revolutions; |r| < 1 for N(0,1) inputs
    float sv, cv;
    asm("v_sin_f32 %0, %1" : "=v"(sv) : "v"(r));
    asm("v_cos_f32 %0, %1" : "=v"(cv) : "v"(r));
    *s = sv; *c = cv;
}

// grid 328 x 256 threads.
// blocks [0,320): kt = bid>>2, sub = bid&3:
//   Wfrag[kt][n=t][dd = sub*8 .. +8] = f16(W[dtile*32+dd][kt%10+1][n])
// blocks [320,328): p = bid-320; c_part[p][h] = sum_{d in p*32..+32} W[d][0][h]+b[d][h]
__global__ void prep_kernel(const float* __restrict__ W, const float* __restrict__ bias,
                            unsigned short* __restrict__ Wfrag, float* __restrict__ c_part) {
    const int bid = blockIdx.x;
    const int t = threadIdx.x;
    if (bid < 4 * NKT) {
        const int kt = bid >> 2;
        const int sub = bid & 3;
        const int dtile = kt / 10;
        const int f = kt - dtile * 10 + 1;
        const int d0 = dtile * 32 + sub * 8;
        const float* wsrc = W + ((size_t)d0 * 11 + f) * 256 + t;
        union { unsigned short s[8]; int4 v; } buf;
#pragma unroll
        for (int dd = 0; dd < 8; ++dd)
            buf.s[dd] = f2h(wsrc[(size_t)dd * 11 * 256]);
        *(int4*)(Wfrag + ((size_t)kt * 256 + t) * 32 + sub * 8) = buf.v;
    } else {
        const int p = bid - 4 * NKT;
        float acc = 0.f;
#pragma unroll
        for (int dd = 0; dd < 32; ++dd) {
            const int d = p * 32 + dd;
            acc += W[(size_t)(d * 11) * 256 + t] + bias[(size_t)d * 256 + t];
        }
        c_part[p * 256 + t] = acc;
    }
}

__global__ __launch_bounds__(512, 2)
void kan_gemm(const float* __restrict__ x, const unsigned short* __restrict__ Wfrag,
              const float* __restrict__ c_part, float* __restrict__ out) {
    __shared__ unsigned short Bs[3 * 20480];   // 3 x 40,960 B = 122,880 B

    const int t = threadIdx.x;
    const int m0 = blockIdx.x * BM;
    const int h0 = blockIdx.y * BN;

    const int lane = t & 63;
    const int wave = t >> 6;         // 0..7
    const int wr = wave >> 1;        // row quarter (32 rows)
    const int wc = wave & 1;         // col half (64 cols)
    const int l15 = lane & 15;
    const int koff = lane >> 4;

    floatx4 acc[2][4];
#pragma unroll
    for (int i = 0; i < 2; ++i)
#pragma unroll
        for (int j = 0; j < 4; ++j)
            acc[i][j] = (floatx4){0.f, 0.f, 0.f, 0.f};

    // lane's x rows: i=0 -> m0 + wr*32 + l15, i=1 -> +16; d-slots koff*8..+8
    const float* xr0 = x + (size_t)(m0 + wr * 32 + l15) * DDIM + koff * 8;

    // ---- prologue: x(dt0) 4 loads, then stage S(0) 5 loads (9 in flight) ----
    float4 xn[4];
    xn[0] = *(const float4*)(xr0 + 0);
    xn[1] = *(const float4*)(xr0 + 4);
    xn[2] = *(const float4*)(xr0 + 16 * DDIM + 0);
    xn[3] = *(const float4*)(xr0 + 16 * DDIM + 4);

    unsigned short* cur = Bs;
    unsigned short* nxt = Bs + 20480;
    unsigned short* thr = Bs + 40960;

#pragma unroll
    for (int s = 0; s < 5; ++s) {
        const int c = wave * 5 + s;
        const int ktl = c >> 3;
        const int f = c & 7;
        const unsigned short* g = Wfrag + (size_t)ktl * 8192
                                + (h0 + f * 16 + l15) * 32 + koff * 8;
        __builtin_amdgcn_global_load_lds((const void*)g, (void*)(cur + c * 512), 16, 0, 0);
    }

    // f16-resident harmonic state: pair p holds elems {2p,2p+1};
    // p 0..3 -> i=0 (d-slots koff*8+0..7), p 4..7 -> i=1.
    __half2 s1h[8], c1h[8], skh[8], ckh[8];

#pragma unroll 1
    for (int ph = 0; ph < 16; ++ph) {
        const int dt = ph >> 1;
        const int half = ph & 1;

        // ---- issue stage(ph+1) into nxt (clamped redundant tail) ----
        {
            int pt = ph + 1;
            if (pt > 15) pt = 15;
#pragma unroll
            for (int s = 0; s < 5; ++s) {
                const int c = wave * 5 + s;
                const int ktl = c >> 3;
                const int f = c & 7;
                const unsigned short* g = Wfrag + (size_t)(pt * 5 + ktl) * 8192
                                        + (h0 + f * 16 + l15) * 32 + koff * 8;
                __builtin_amdgcn_global_load_lds((const void*)g, (void*)(nxt + c * 512), 16, 0, 0);
            }
        }

        // x prefetch for next dtile on ODD phases (consumed at next even
        // phase's sincos; current sincos already done a phase ago).
        if (half == 1) {
            const int dn = (dt < 7) ? dt + 1 : 7;
            xn[0] = *(const float4*)(xr0 + dn * 32 + 0);
            xn[1] = *(const float4*)(xr0 + dn * 32 + 4);
            xn[2] = *(const float4*)(xr0 + 16 * DDIM + dn * 32 + 0);
            xn[3] = *(const float4*)(xr0 + 16 * DDIM + dn * 32 + 4);
        }

        // ---- counted wait (even: 5, odd: 9 — audited) + publish barrier ----
        __builtin_amdgcn_sched_barrier(0);
        if (half == 0) {
            asm volatile("s_waitcnt vmcnt(5)" ::: "memory");
        } else {
            asm volatile("s_waitcnt vmcnt(9)" ::: "memory");
        }
        __builtin_amdgcn_s_barrier();
        __builtin_amdgcn_sched_barrier(0);

        if (half == 0) {
            // ---- dtile start: hw sincos of 16 elems -> f16 state ----
#pragma unroll
            for (int p = 0; p < 8; ++p) {
                float s0, c0, s1, c1;
                const float xv0 = ((const float*)&xn[p >> 1])[(p & 1) * 2];
                const float xv1 = ((const float*)&xn[p >> 1])[(p & 1) * 2 + 1];
                hwsincos(xv0, &s0, &c0);
                hwsincos(xv1, &s1, &c1);
                const __half2 sh = __floats2half2_rn(s0, s1);
                const __half2 ch = __floats2half2_rn(c0, c1);
                s1h[p] = sh; c1h[p] = ch;
                skh[p] = sh; ckh[p] = ch;
            }
        }

        // ---- compute 5 kt of this half-dtile ----
#pragma unroll
        for (int kl = 0; kl < 5; ++kl) {
            const int hs = half * 5 + kl;            // 0..9 within dtile

            union { __half2 h2[4]; halfx8 v; } a0, a1;
            if (hs & 1) {   // cos(kx)
#pragma unroll
                for (int p = 0; p < 4; ++p) { a0.h2[p] = ckh[p]; a1.h2[p] = ckh[p + 4]; }
            } else {        // sin(kx)
#pragma unroll
                for (int p = 0; p < 4; ++p) { a0.h2[p] = skh[p]; a1.h2[p] = skh[p + 4]; }
            }

            const unsigned short* fb = cur + (kl * 8 + wc * 4) * 512 + lane * 8;
            const halfx8 b0 = *(const halfx8*)(fb);
            const halfx8 b1 = *(const halfx8*)(fb + 512);
            const halfx8 b2 = *(const halfx8*)(fb + 1024);
            const halfx8 b3 = *(const halfx8*)(fb + 1536);

            acc[0][0] = __builtin_amdgcn_mfma_f32_16x16x32_f16(a0.v, b0, acc[0][0], 0, 0, 0);
            acc[1][0] = __builtin_amdgcn_mfma_f32_16x16x32_f16(a1.v, b0, acc[1][0], 0, 0, 0);
            acc[0][1] = __builtin_amdgcn_mfma_f32_16x16x32_f16(a0.v, b1, acc[0][1], 0, 0, 0);
            acc[1][1] = __builtin_amdgcn_mfma_f32_16x16x32_f16(a1.v, b1, acc[1][1], 0, 0, 0);
            acc[0][2] = __builtin_amdgcn_mfma_f32_16x16x32_f16(a0.v, b2, acc[0][2], 0, 0, 0);
            acc[1][2] = __builtin_amdgcn_mfma_f32_16x16x32_f16(a1.v, b2, acc[1][2], 0, 0, 0);
            acc[0][3] = __builtin_amdgcn_mfma_f32_16x16x32_f16(a0.v, b3, acc[0][3], 0, 0, 0);
            acc[1][3] = __builtin_amdgcn_mfma_f32_16x16x32_f16(a1.v, b3, acc[1][3], 0, 0, 0);

            // advance harmonic k -> k+1 after each cos emit (except k=5):
            // ns = sk*c1 + ck*s1 ; nc = ck*c1 - sk*s1 (packed fp16)
            if ((hs & 1) && hs < 9) {
#pragma unroll
                for (int p = 0; p < 8; ++p) {
                    const __half2 t0 = __hmul2(ckh[p], s1h[p]);
                    const __half2 t1 = __hmul2(skh[p], s1h[p]);
                    const __half2 ns = __hfma2(skh[p], c1h[p], t0);
                    const __half2 nc = __hfma2(ckh[p], c1h[p], __hneg2(t1));
                    skh[p] = ns;
                    ckh[p] = nc;
                }
            }
        }

        // rotate ring pointers
        unsigned short* tmp = cur;
        cur = nxt;
        nxt = thr;
        thr = tmp;
    }

    // drain redundant tail DMAs
    asm volatile("s_waitcnt vmcnt(0)" ::: "memory");

    // ---- epilogue: C/D layout col=lane&15, row=(lane>>4)*4+reg ----
    float cj[4];
#pragma unroll
    for (int j = 0; j < 4; ++j) {
        const int col = h0 + wc * 64 + j * 16 + l15;
        float s = 0.f;
#pragma unroll
        for (int q = 0; q < 8; ++q) s += c_part[q * 256 + col];
        cj[j] = s;
    }
#pragma unroll
    for (int i = 0; i < 2; ++i) {
        const int row0 = m0 + wr * 32 + i * 16 + koff * 4;
#pragma unroll
        for (int j = 0; j < 4; ++j) {
            const int col = h0 + wc * 64 + j * 16 + l15;
#pragma unroll
            for (int r = 0; r < 4; ++r)
                out[(size_t)(row0 + r) * HOUT + col] = acc[i][j][r] + cj[j];
        }
    }
}

extern "C" void kernel_launch(void* const* d_in, const int* in_sizes, int n_in,
                              void* d_out, int out_size, void* d_ws, size_t ws_size,
                              hipStream_t stream) {
    const float* x = (const float*)d_in[0];
    const float* W = (const float*)d_in[1];
    const float* b = (const float*)d_in[2];
    float* out = (float*)d_out;

    unsigned short* Wfrag = (unsigned short*)d_ws;                      // 1,310,720 B
    float* c_part = (float*)((char*)d_ws + (size_t)NKT * 256 * 32 * 2); // 8 KB

    prep_kernel<<<4 * NKT + 8, 256, 0, stream>>>(W, b, Wfrag, c_part);
    kan_gemm<<<dim3(BDIM / BM, HOUT / BN), 512, 0, stream>>>(x, Wfrag, c_part, out);
}